// Round 4
// baseline (2614.206 us; speedup 1.0000x reference)
//
#include <hip/hip_runtime.h>

// x[t,b,h] = input·W_ihT + b_ih + hidden·W_hhT + b_hh  (M=32768, N=512, K=512+512)
// then in-place LIF scan over t.
// ARITHMETIC IS BIT-IDENTICAL TO THE ROUND-1 PASSING KERNEL: per output,
// ascending-k fmaf chain per phase (acc1: input·W_ih, acc2: hidden·W_hh),
// epilogue ((acc1 + b_ih) + acc2) + b_hh. Only scheduling/layout changed.

constexpr int BM = 128, BN = 64, BK = 32;

// 16B-chunk XOR swizzle within each 128B LDS row. Round-1-proven form:
// reads (rows tm*8+i: row>>3 = tm distinct per wave) -> distinct clusters,
// conflict-free; staging writes hit each cluster uniformly (b128 BW floor).
__device__ __forceinline__ int fsw(int row) { return ((row >> 3) ^ row) & 7; }

#define STAGE_LOAD(AP, WP)                                                    \
    _Pragma("unroll") for (int q = 0; q < 4; ++q)                             \
        ar[q] = *(const float4*)((AP) + aoff[q]);                             \
    _Pragma("unroll") for (int q = 0; q < 2; ++q)                             \
        wr[q] = *(const float4*)((WP) + woff[q]);

#define STAGE_STORE(PW)                                                       \
    _Pragma("unroll") for (int q = 0; q < 4; ++q)                             \
        *(float4*)(&As[PW][awr[q]]) = ar[q];                                  \
    _Pragma("unroll") for (int q = 0; q < 2; ++q)                             \
        *(float4*)(&Ws[PW][wwr[q]]) = wr[q];

// Per output acc[i][j]: k ascending (kc ascending, xyzw within chunk) —
// identical fma chain to round 1.
#define FMA_PHASE(ACC, PR)                                                    \
    _Pragma("unroll")                                                         \
    for (int kc = 0; kc < 8; ++kc) {                                          \
        float4 w4[4];                                                         \
        _Pragma("unroll")                                                     \
        for (int j = 0; j < 4; ++j) {                                         \
            const int wrow = tn * 4 + j;                                      \
            w4[j] = *(const float4*)(&Ws[PR][wrow * 32 + (((kc ^ fsw(wrow)) & 7) << 2)]); \
        }                                                                     \
        _Pragma("unroll")                                                     \
        for (int i = 0; i < 8; ++i) {                                         \
            const int arow = tm * 8 + i;                                      \
            const float4 a4 = *(const float4*)(&As[PR][arow * 32 + (((kc ^ fsw(arow)) & 7) << 2)]); \
            _Pragma("unroll")                                                 \
            for (int j = 0; j < 4; ++j) {                                     \
                ACC[i][j] = fmaf(a4.x, w4[j].x, ACC[i][j]);                   \
                ACC[i][j] = fmaf(a4.y, w4[j].y, ACC[i][j]);                   \
                ACC[i][j] = fmaf(a4.z, w4[j].z, ACC[i][j]);                   \
                ACC[i][j] = fmaf(a4.w, w4[j].w, ACC[i][j]);                   \
            }                                                                 \
        }                                                                     \
    }

__global__ __launch_bounds__(256, 2) void gemm_x(
    const float* __restrict__ input, const float* __restrict__ hidden,
    const float* __restrict__ W_ih, const float* __restrict__ b_ih,
    const float* __restrict__ W_hh, const float* __restrict__ b_hh,
    float* __restrict__ out)
{
    // Double-buffered tiles: A [128][32] f32 (16K) + W [64][32] (8K), x2 = 48 KiB.
    __shared__ __align__(16) float As[2][BM * BK];
    __shared__ __align__(16) float Ws[2][BN * BK];

    const int tid = threadIdx.x;
    // XCD-chunked swizzle: XCD x owns 256 consecutive tiles (bm-major), so the
    // 8 bn-tiles sharing an A-panel are resident in one XCD's L2.
    const int tile = ((blockIdx.x & 7) << 8) | (blockIdx.x >> 3);
    const int bm = tile >> 3, bn = tile & 7;       // 256 x 8 tiles of 128x64
    const int m0 = bm * 128, n0 = bn * 64;
    const int tm = tid >> 4, tn = tid & 15;        // 8x4 outputs per thread

    int aoff[4], awr[4], woff[2], wwr[2];
#pragma unroll
    for (int q = 0; q < 4; ++q) {
        int lin = q * 256 + tid, row = lin >> 3, s4 = lin & 7;
        aoff[q] = (m0 + row) * 512 + s4 * 4;
        awr[q]  = row * 32 + ((s4 ^ fsw(row)) << 2);
    }
#pragma unroll
    for (int q = 0; q < 2; ++q) {
        int lin = q * 256 + tid, row = lin >> 3, s4 = lin & 7;
        woff[q] = (n0 + row) * 512 + s4 * 4;
        wwr[q]  = row * 32 + ((s4 ^ fsw(row)) << 2);
    }

    float acc1[8][4], acc2[8][4];
#pragma unroll
    for (int i = 0; i < 8; ++i)
#pragma unroll
        for (int j = 0; j < 4; ++j) { acc1[i][j] = 0.f; acc2[i][j] = 0.f; }

    float4 ar[4], wr[2];
    // Prologue: tile 0 -> buf 0.
    STAGE_LOAD(input, W_ih);
    STAGE_STORE(0);
    __syncthreads();

    // Phase 1: input · W_ih^T. Tile kt lives in buf (kt&1); one barrier/tile.
#pragma unroll 1
    for (int kt = 0; kt < 16; ++kt) {
        const int pr = kt & 1;
        const float* An = (kt < 15) ? (input + (kt + 1) * 32) : hidden;
        const float* Wn = (kt < 15) ? (W_ih + (kt + 1) * 32) : W_hh;
        STAGE_LOAD(An, Wn);            // issue next-tile loads (latency under fma)
        FMA_PHASE(acc1, pr);
        STAGE_STORE(pr ^ 1);           // vmcnt wait lands here, after fma phase
        __syncthreads();
    }
    // Phase 2: hidden · W_hh^T. Global tile g = 16+kt, parity g&1 = kt&1.
#pragma unroll 1
    for (int kt = 0; kt < 16; ++kt) {
        const int pr = kt & 1;
        if (kt < 15) {
            const float* An = hidden + (kt + 1) * 32;
            const float* Wn = W_hh + (kt + 1) * 32;
            STAGE_LOAD(An, Wn);
        }
        FMA_PHASE(acc2, pr);
        if (kt < 15) {
            STAGE_STORE(pr ^ 1);
            __syncthreads();
        }
    }

    // Epilogue: x = ((dot1 + b_ih) + dot2) + b_hh  (exact round-1 association)
    const float4 bi4 = *(const float4*)(b_ih + n0 + tn * 4);
    const float4 bh4 = *(const float4*)(b_hh + n0 + tn * 4);
#pragma unroll
    for (int i = 0; i < 8; ++i) {
        float4 o;
        o.x = ((acc1[i][0] + bi4.x) + acc2[i][0]) + bh4.x;
        o.y = ((acc1[i][1] + bi4.y) + acc2[i][1]) + bh4.y;
        o.z = ((acc1[i][2] + bi4.z) + acc2[i][2]) + bh4.z;
        o.w = ((acc1[i][3] + bi4.w) + acc2[i][3]) + bh4.w;
        *(float4*)(out + (size_t)(m0 + tm * 8 + i) * 512 + n0 + tn * 4) = o;
    }
}

// In-place LIF scan: one thread per (b,h) lane, sequential over t.
// Same per-element float ops as the passing rounds.
__global__ __launch_bounds__(256) void lif_scan(float* __restrict__ x)
{
    const int tid = blockIdx.x * blockDim.x + threadIdx.x;  // 0..32767
    float v = 0.f;
    for (int tb = 0; tb < 512; tb += 16) {
        float xv[16];
#pragma unroll
        for (int u = 0; u < 16; ++u)
            xv[u] = x[(tb + u) * 32768 + tid];
#pragma unroll
        for (int u = 0; u < 16; ++u) {
            v = v + (xv[u] - v) * 0.5f;
            float s = (v - 1.0f >= 0.0f) ? 1.0f : 0.0f;
            x[(tb + u) * 32768 + tid] = s;
            v = (1.0f - s) * v;
        }
    }
}

extern "C" void kernel_launch(void* const* d_in, const int* in_sizes, int n_in,
                              void* d_out, int out_size, void* d_ws, size_t ws_size,
                              hipStream_t stream) {
    const float* input  = (const float*)d_in[0];
    const float* hidden = (const float*)d_in[1];
    const float* W_ih   = (const float*)d_in[2];
    const float* b_ih   = (const float*)d_in[3];
    const float* W_hh   = (const float*)d_in[4];
    const float* b_hh   = (const float*)d_in[5];
    float* out = (float*)d_out;

    gemm_x<<<dim3(2048), dim3(256), 0, stream>>>(
        input, hidden, W_ih, b_ih, W_hh, b_hh, out);
    lif_scan<<<dim3(128), dim3(256), 0, stream>>>(out);
}

// Round 5
// 1008.898 us; speedup vs baseline: 2.5912x; 2.5912x over previous
//
#include <hip/hip_runtime.h>
#include <stdint.h>

// x[t,b,h] = input·W_ihT + b_ih + hidden·W_hhT + b_hh  (M=32768, N=512, K=512+512)
// then in-place LIF scan over t.
// ARITHMETIC IS BIT-IDENTICAL TO THE ROUND-1 PASSING KERNEL: per output,
// ascending-k fmaf chain per phase (acc1: input·W_ih, acc2: hidden·W_hh),
// epilogue ((acc1 + b_ih) + acc2) + b_hh. Only staging/scheduling changed:
// global_load_lds (async, no VGPR round-trip — round-4's reg-prefetch spilled),
// double-buffered LDS, one barrier per K-tile, XCD-chunked block swizzle.

constexpr int BM = 128, BN = 64, BK = 32;

// 16B-chunk XOR swizzle within each 128B LDS row (round-1-proven):
// FMA reads: A rows tm*8+i (4 distinct tm/wave) -> 4 distinct bank-quads,
// conflict-free; W rows tn*4+j -> 2-way (free, m136).
__device__ __forceinline__ int fsw(int row) { return ((row >> 3) ^ row) & 7; }

typedef float __attribute__((address_space(1))) gfloat;
typedef float __attribute__((address_space(3))) lfloat;

// Async 16B global->LDS: LDS dest = wave-uniform base + lane*16 (linear);
// the swizzled layout is realized by pre-swizzling the per-lane GLOBAL source.
#define GLL16(GP, LP)                                                         \
    __builtin_amdgcn_global_load_lds((const gfloat*)(GP), (lfloat*)(LP), 16, 0, 0)

// Issue the 6 per-thread loads for one K-tile (A: 4 wave-instr, W: 2).
#define STAGE(AB, WB, KB, BUF) do {                                           \
    _Pragma("unroll") for (int q = 0; q < 4; ++q)                             \
        GLL16((AB) + ga[q] + (KB), &As[BUF][la[q]]);                          \
    _Pragma("unroll") for (int q = 0; q < 2; ++q)                             \
        GLL16((WB) + gw[q] + (KB), &Ws[BUF][lw[q]]);                          \
} while (0)

// Per output acc[i][j]: k ascending (kc ascending, xyzw within chunk) —
// identical fma chain to round 1.
#define FMA_PHASE(ACC, PR)                                                    \
    _Pragma("unroll")                                                         \
    for (int kc = 0; kc < 8; ++kc) {                                          \
        float4 w4[4];                                                         \
        _Pragma("unroll")                                                     \
        for (int j = 0; j < 4; ++j) {                                         \
            const int wrow = tn * 4 + j;                                      \
            w4[j] = *(const float4*)(&Ws[PR][wrow * 32 + (((kc ^ fsw(wrow)) & 7) << 2)]); \
        }                                                                     \
        _Pragma("unroll")                                                     \
        for (int i = 0; i < 8; ++i) {                                         \
            const int arow = tm * 8 + i;                                      \
            const float4 a4 = *(const float4*)(&As[PR][arow * 32 + (((kc ^ fsw(arow)) & 7) << 2)]); \
            _Pragma("unroll")                                                 \
            for (int j = 0; j < 4; ++j) {                                     \
                ACC[i][j] = fmaf(a4.x, w4[j].x, ACC[i][j]);                   \
                ACC[i][j] = fmaf(a4.y, w4[j].y, ACC[i][j]);                   \
                ACC[i][j] = fmaf(a4.z, w4[j].z, ACC[i][j]);                   \
                ACC[i][j] = fmaf(a4.w, w4[j].w, ACC[i][j]);                   \
            }                                                                 \
        }                                                                     \
    }

__global__ __launch_bounds__(256, 2) void gemm_x(
    const float* __restrict__ input, const float* __restrict__ hidden,
    const float* __restrict__ W_ih, const float* __restrict__ b_ih,
    const float* __restrict__ W_hh, const float* __restrict__ b_hh,
    float* __restrict__ out)
{
    // Double-buffered tiles: A [128][32] f32 + W [64][32] f32, x2 = 48 KiB
    // -> 3 blocks/CU (12 waves). Layout: row-major rows of 8 16B-chunks,
    // physical chunk = logical chunk ^ fsw(row).
    __shared__ __align__(16) float As[2][BM * BK];
    __shared__ __align__(16) float Ws[2][BN * BK];

    const int tid = threadIdx.x;
    const int w = tid >> 6, l = tid & 63;
    // XCD-chunked swizzle: XCD x owns 256 consecutive tiles (bm-major) so the
    // 8 bn-tiles sharing an A-panel are dispatch-adjacent within one XCD's L2.
    const int tile = ((blockIdx.x & 7) << 8) | (blockIdx.x >> 3);
    const int bm = tile >> 3, bn = tile & 7;       // 256 x 8 tiles of 128x64
    const int m0 = bm * 128, n0 = bn * 64;
    const int tm = tid >> 4, tn = tid & 15;        // 8x4 outputs per thread

    // Staging maps: physical chunk p -> (row = p>>3, logical s4 = (p&7)^fsw(row)).
    // ga/gw: per-lane global f32 offset (kb added per tile); la/lw: wave-uniform
    // LDS f32 base (lane*16B appended by hardware).
    int ga[4], la[4], gw[2], lw[2];
#pragma unroll
    for (int q = 0; q < 4; ++q) {
        int p = (w * 4 + q) * 64 + l;
        int row = p >> 3, s4 = (p & 7) ^ fsw(row);
        ga[q] = (m0 + row) * 512 + s4 * 4;
        la[q] = (w * 4 + q) * 256;
    }
#pragma unroll
    for (int q = 0; q < 2; ++q) {
        int p = (w * 2 + q) * 64 + l;
        int row = p >> 3, s4 = (p & 7) ^ fsw(row);
        gw[q] = (n0 + row) * 512 + s4 * 4;
        lw[q] = (w * 2 + q) * 256;
    }

    float acc1[8][4], acc2[8][4];
#pragma unroll
    for (int i = 0; i < 8; ++i)
#pragma unroll
        for (int j = 0; j < 4; ++j) { acc1[i][j] = 0.f; acc2[i][j] = 0.f; }

    // Prologue: tile 0 -> buf 0; barrier drains vmcnt.
    STAGE(input, W_ih, 0, 0);
    __syncthreads();

    // Unified 32-tile loop (16 input·W_ih + 16 hidden·W_hh), one barrier/tile.
    // Loads for tile kt+1 fly under the FMA phase on tile kt.
#pragma unroll 1
    for (int kt = 0; kt < 32; ++kt) {
        const int cur = kt & 1;
        if (kt < 31) {
            const int nk = kt + 1;
            const float* Ab = (nk < 16) ? input : hidden;
            const float* Wb = (nk < 16) ? W_ih : W_hh;
            STAGE(Ab, Wb, (nk & 15) * 32, cur ^ 1);
        }
        if (kt < 16) { FMA_PHASE(acc1, cur) }
        else         { FMA_PHASE(acc2, cur) }
        __syncthreads();
    }

    // Epilogue: x = ((dot1 + b_ih) + dot2) + b_hh  (exact round-1 association)
    const float4 bi4 = *(const float4*)(b_ih + n0 + tn * 4);
    const float4 bh4 = *(const float4*)(b_hh + n0 + tn * 4);
#pragma unroll
    for (int i = 0; i < 8; ++i) {
        float4 o;
        o.x = ((acc1[i][0] + bi4.x) + acc2[i][0]) + bh4.x;
        o.y = ((acc1[i][1] + bi4.y) + acc2[i][1]) + bh4.y;
        o.z = ((acc1[i][2] + bi4.z) + acc2[i][2]) + bh4.z;
        o.w = ((acc1[i][3] + bi4.w) + acc2[i][3]) + bh4.w;
        *(float4*)(out + (size_t)(m0 + tm * 8 + i) * 512 + n0 + tn * 4) = o;
    }
}

// In-place LIF scan: one thread per (b,h) lane, sequential over t.
// Same per-element float ops as the passing rounds.
__global__ __launch_bounds__(256) void lif_scan(float* __restrict__ x)
{
    const int tid = blockIdx.x * blockDim.x + threadIdx.x;  // 0..32767
    float v = 0.f;
    for (int tb = 0; tb < 512; tb += 16) {
        float xv[16];
#pragma unroll
        for (int u = 0; u < 16; ++u)
            xv[u] = x[(tb + u) * 32768 + tid];
#pragma unroll
        for (int u = 0; u < 16; ++u) {
            v = v + (xv[u] - v) * 0.5f;
            float s = (v - 1.0f >= 0.0f) ? 1.0f : 0.0f;
            x[(tb + u) * 32768 + tid] = s;
            v = (1.0f - s) * v;
        }
    }
}

extern "C" void kernel_launch(void* const* d_in, const int* in_sizes, int n_in,
                              void* d_out, int out_size, void* d_ws, size_t ws_size,
                              hipStream_t stream) {
    const float* input  = (const float*)d_in[0];
    const float* hidden = (const float*)d_in[1];
    const float* W_ih   = (const float*)d_in[2];
    const float* b_ih   = (const float*)d_in[3];
    const float* W_hh   = (const float*)d_in[4];
    const float* b_hh   = (const float*)d_in[5];
    float* out = (float*)d_out;

    gemm_x<<<dim3(2048), dim3(256), 0, stream>>>(
        input, hidden, W_ih, b_ih, W_hh, b_hh, out);
    lif_scan<<<dim3(128), dim3(256), 0, stream>>>(out);
}